// Round 1
// baseline (817.144 us; speedup 1.0000x reference)
//
#include <hip/hip_runtime.h>
#include <math.h>

#define NNODES 1048576
#define NSEG   8192
#define DIN    128
#define DH     64

typedef __bf16 bf16x8 __attribute__((ext_vector_type(8)));
typedef float  f32x4  __attribute__((ext_vector_type(4)));

// ---------------- prep kernel 1: node -> segment id ----------------
__global__ void seg_fill_kernel(const int* __restrict__ offset, int* __restrict__ seg_id) {
    int s = blockIdx.x;
    int start = offset[s], end = offset[s + 1];
    for (int i = start + (int)threadIdx.x; i < end; i += (int)blockDim.x) seg_id[i] = s;
}

// ---------------- prep kernel 2: fold attention (seq len 1 => attn == 1, ctx == v) ----
// out = tokens @ (out_w @ Wv)^T + (out_w @ bv + out_b)
// Writes M transposed: Mt[k*64 + i] = M[i][k]  (for conflict-free LDS reads later)
__global__ void fold_kernel(const float* __restrict__ in_proj_w, const float* __restrict__ in_proj_b,
                            const float* __restrict__ out_w, const float* __restrict__ out_b,
                            float* __restrict__ Mt, float* __restrict__ bfold) {
    int t = blockIdx.x * blockDim.x + threadIdx.x;   // 0..4095 over 16 blocks x 256
    int i = t >> 6, j = t & 63;
    const float* Wv = in_proj_w + 2 * DH * DH;       // third 64-row block
    float sum = 0.f;
#pragma unroll 8
    for (int k = 0; k < DH; ++k) sum += out_w[i * DH + k] * Wv[k * DH + j];
    Mt[j * DH + i] = sum;
    if (t < DH) {
        const float* bv = in_proj_b + 2 * DH;
        float s2 = out_b[t];
#pragma unroll 8
        for (int k = 0; k < DH; ++k) s2 += out_w[t * DH + k] * bv[k];
        bfold[t] = s2;
    }
}

// ---------------- main fused kernel: 2-layer MLP (bf16 MFMA) + segment sum ----------
// grid 4096 blocks x 256 threads; each wave handles 64 consecutive nodes (4 subtiles of 16).
// MFMA 16x16x32 bf16. A-frag: lane holds row m=lane&15, k=(lane>>4)*8+j.
// B-frag (from B^T rows, i.e. W[n][k]): lane holds col n=lane&15, same k pattern.
// C/D: col=lane&15, row=(lane>>4)*4+reg.
__launch_bounds__(256, 2)
__global__ void mlp_seg_kernel(const float* __restrict__ x, const int* __restrict__ seg_id,
                               const float* __restrict__ W1, const float* __restrict__ b1,
                               const float* __restrict__ W2, const float* __restrict__ b2,
                               float* __restrict__ tokens) {
    const int tid  = threadIdx.x;
    const int w    = tid >> 6;
    const int lane = tid & 63;
    const int quad = lane >> 4;
    const int col  = lane & 15;

    // per-wave h1 transpose buffer: 16 nodes x 80 bf16 (row stride 160 B, 16B aligned,
    // bank advance 8/row -> ~4-way on b128 reads, acceptable; no __syncthreads needed)
    __shared__ __align__(16) __bf16 h1buf[4][16][80];

    // ---- stage weight fragments into registers (once per block) ----
    bf16x8 w1f[4][4];   // [nt][kt], n = nt*16+col, k = kt*32+quad*8..+7
#pragma unroll
    for (int nt = 0; nt < 4; ++nt)
#pragma unroll
        for (int kt = 0; kt < 4; ++kt) {
            const float* wp = W1 + (nt * 16 + col) * DIN + kt * 32 + quad * 8;
#pragma unroll
            for (int j = 0; j < 8; ++j) w1f[nt][kt][j] = (__bf16)wp[j];
        }
    bf16x8 w2f[4][2];
#pragma unroll
    for (int nt = 0; nt < 4; ++nt)
#pragma unroll
        for (int kt = 0; kt < 2; ++kt) {
            const float* wp = W2 + (nt * 16 + col) * DH + kt * 32 + quad * 8;
#pragma unroll
            for (int j = 0; j < 8; ++j) w2f[nt][kt][j] = (__bf16)wp[j];
        }
    float b1v[4], b2v[4];
#pragma unroll
    for (int nt = 0; nt < 4; ++nt) {
        b1v[nt] = b1[nt * 16 + col];
        b2v[nt] = b2[nt * 16 + col];
    }

#pragma unroll
    for (int sub = 0; sub < 4; ++sub) {
        const int node_base = blockIdx.x * 256 + w * 64 + sub * 16;

        // ---- A-frags: x rows, direct from global (64B contiguous per 4 lanes) ----
        const float4* xp = (const float4*)(x + (size_t)(node_base + col) * DIN + quad * 8);
        bf16x8 a[4];
#pragma unroll
        for (int kt = 0; kt < 4; ++kt) {
            float4 u  = xp[kt * 8];
            float4 v2 = xp[kt * 8 + 1];
            a[kt][0] = (__bf16)u.x;  a[kt][1] = (__bf16)u.y;
            a[kt][2] = (__bf16)u.z;  a[kt][3] = (__bf16)u.w;
            a[kt][4] = (__bf16)v2.x; a[kt][5] = (__bf16)v2.y;
            a[kt][6] = (__bf16)v2.z; a[kt][7] = (__bf16)v2.w;
        }
        int seg_lane = seg_id[node_base + col];   // 16 distinct ints, broadcast across quads

        // ---- layer 1: (16x128) @ (128x64) ----
        f32x4 acc1[4];
#pragma unroll
        for (int nt = 0; nt < 4; ++nt) acc1[nt] = (f32x4){0.f, 0.f, 0.f, 0.f};
#pragma unroll
        for (int kt = 0; kt < 4; ++kt)
#pragma unroll
            for (int nt = 0; nt < 4; ++nt)
                acc1[nt] = __builtin_amdgcn_mfma_f32_16x16x32_bf16(a[kt], w1f[nt][kt], acc1[nt], 0, 0, 0);

        // bias + relu, C-layout -> A-layout via per-wave LDS
#pragma unroll
        for (int nt = 0; nt < 4; ++nt)
#pragma unroll
            for (int r = 0; r < 4; ++r) {
                float v = fmaxf(acc1[nt][r] + b1v[nt], 0.f);
                h1buf[w][quad * 4 + r][nt * 16 + col] = (__bf16)v;
            }

        bf16x8 a2[2];
#pragma unroll
        for (int kt = 0; kt < 2; ++kt)
            a2[kt] = *(const bf16x8*)&h1buf[w][col][kt * 32 + quad * 8];

        // ---- layer 2: (16x64) @ (64x64) ----
        f32x4 acc2[4];
#pragma unroll
        for (int nt = 0; nt < 4; ++nt) acc2[nt] = (f32x4){0.f, 0.f, 0.f, 0.f};
#pragma unroll
        for (int kt = 0; kt < 2; ++kt)
#pragma unroll
            for (int nt = 0; nt < 4; ++nt)
                acc2[nt] = __builtin_amdgcn_mfma_f32_16x16x32_bf16(a2[kt], w2f[nt][kt], acc2[nt], 0, 0, 0);

        float hv[4][4];
#pragma unroll
        for (int nt = 0; nt < 4; ++nt)
#pragma unroll
            for (int r = 0; r < 4; ++r)
                hv[nt][r] = fmaxf(acc2[nt][r] + b2v[nt], 0.f);

        // ---- segmented sum over the 16 nodes ----
        int s0 = __shfl(seg_lane, 0);
        int s1 = __shfl(seg_lane, 15);
        if (s0 == s1) {
            // whole subtile in one segment (~88% of subtiles): full reduce, 1 atomic inst
            float p[4];
#pragma unroll
            for (int nt = 0; nt < 4; ++nt) {
                p[nt] = hv[nt][0] + hv[nt][1] + hv[nt][2] + hv[nt][3];
                p[nt] += __shfl_xor(p[nt], 16);
                p[nt] += __shfl_xor(p[nt], 32);
            }
            float val = (quad == 0) ? p[0] : (quad == 1) ? p[1] : (quad == 2) ? p[2] : p[3];
            atomicAdd(&tokens[s0 * DH + quad * 16 + col], val);
        } else {
            // subtile spans segments: per-node atomics
            int segs[4];
#pragma unroll
            for (int r = 0; r < 4; ++r) segs[r] = __shfl(seg_lane, quad * 4 + r);
#pragma unroll
            for (int nt = 0; nt < 4; ++nt)
#pragma unroll
                for (int r = 0; r < 4; ++r)
                    atomicAdd(&tokens[segs[r] * DH + nt * 16 + col], hv[nt][r]);
        }
    }
}

// ---------------- final projection: out[s] = tokens[s] @ M^T + bfold ----------------
__global__ void out_kernel(const float* __restrict__ tokens, const float* __restrict__ Mt,
                           const float* __restrict__ bfold, float* __restrict__ out) {
    __shared__ float mt[DH * DH];
    __shared__ float bf[DH];
    for (int i = threadIdx.x; i < DH * DH; i += 256) mt[i] = Mt[i];
    if (threadIdx.x < DH) bf[threadIdx.x] = bfold[threadIdx.x];
    __syncthreads();
    int sl = threadIdx.x >> 6;
    int d  = threadIdx.x & 63;
    int s  = blockIdx.x * 4 + sl;
    const float* trow = tokens + s * DH;
    float sum = bf[d];
#pragma unroll 16
    for (int k = 0; k < DH; ++k) sum += trow[k] * mt[k * DH + d];  // mt read conflict-free
    out[s * DH + d] = sum;
}

extern "C" void kernel_launch(void* const* d_in, const int* in_sizes, int n_in,
                              void* d_out, int out_size, void* d_ws, size_t ws_size,
                              hipStream_t stream) {
    const float* x         = (const float*)d_in[0];
    const int*   offset    = (const int*)d_in[1];
    const float* W1        = (const float*)d_in[2];
    const float* b1        = (const float*)d_in[3];
    const float* W2        = (const float*)d_in[4];
    const float* b2        = (const float*)d_in[5];
    const float* in_proj_w = (const float*)d_in[6];
    const float* in_proj_b = (const float*)d_in[7];
    const float* out_w     = (const float*)d_in[8];
    const float* out_b     = (const float*)d_in[9];
    float* out = (float*)d_out;

    char* ws = (char*)d_ws;
    float* tokens = (float*)ws;                                   // 8192*64*4 = 2 MB
    int*   seg_id = (int*)(ws + (size_t)NSEG * DH * 4);           // 4 MB
    float* Mt     = (float*)(ws + (size_t)NSEG * DH * 4 + (size_t)NNODES * 4); // 16 KB
    float* bfold  = Mt + DH * DH;                                 // 256 B

    hipMemsetAsync(tokens, 0, (size_t)NSEG * DH * sizeof(float), stream);
    seg_fill_kernel<<<NSEG, 64, 0, stream>>>(offset, seg_id);
    fold_kernel<<<16, 256, 0, stream>>>(in_proj_w, in_proj_b, out_w, out_b, Mt, bfold);
    mlp_seg_kernel<<<NNODES / 256, 256, 0, stream>>>(x, seg_id, W1, b1, W2, b2, tokens);
    out_kernel<<<NSEG / 4, 256, 0, stream>>>(tokens, Mt, bfold, out);
}